// Round 2
// baseline (867.706 us; speedup 1.0000x reference)
//
#include <hip/hip_runtime.h>
#include <hip/hip_bf16.h>

#define N_NODES 131072
#define N_EDGES 2097152
#define IN_DIM 768
#define HID 64
#define NPG 32
#define NGRAPH (N_NODES / NPG)   // 4096

#define BM 128
#define KC 64
#define LDP (KC + 8)
#define GEMM_BLOCKS (N_NODES / BM)    // 1024

// ---- radix partition geometry: ranges of 128 nodes = 4 whole graphs ----
#define RNG 128
#define NB (N_NODES / RNG)            // 1024 buckets
#define EPB 4096                      // edges per count/scatter block
#define NCB (N_EDGES / EPB)           // 512 blocks
#define PBLK 8                        // prefix stage-A blocks
#define RPB (NCB / PBLK)              // 64 rows per stage-A block
#define PREP_BLK 192                  // blocks for W transpose

typedef __attribute__((ext_vector_type(8))) short bf16x8;
typedef __attribute__((ext_vector_type(4))) float f32x4;

static __device__ __forceinline__ unsigned short f2bf(float f) {
    __hip_bfloat16 h = __float2bfloat16(f);  // hardware RNE cvt
    return *reinterpret_cast<unsigned short*>(&h);
}
static __device__ __forceinline__ float bf2f(unsigned short s) {
    return __uint_as_float(((unsigned int)s) << 16);
}

// ---- k1: W transpose (blocks < PREP_BLK) + per-block bucket histogram ----
// count path: LDS 1024-bin histogram (NO global atomics), C[cb][bkt] out.
__global__ __launch_bounds__(256) void gcn_prep_count(const float* __restrict__ W,
                                                      unsigned short* __restrict__ Wt,
                                                      const int* __restrict__ dst,
                                                      unsigned int* __restrict__ C) {
    __shared__ unsigned int hist[NB];
    int tid = threadIdx.x;
    if (blockIdx.x < PREP_BLK) {
        int i = blockIdx.x * 256 + tid;
        if (i < IN_DIM * HID) {
            int k = i >> 6, n = i & 63;
            Wt[n * IN_DIM + k] = f2bf(W[i]);
        }
        return;
    }
    int cb = blockIdx.x - PREP_BLK;
    for (int t = tid; t < NB; t += 256) hist[t] = 0u;
    __syncthreads();
    int base = cb * EPB;
    #pragma unroll
    for (int u = 0; u < EPB / 256; ++u) {
        int d = dst[base + u * 256 + tid];
        atomicAdd(&hist[d >> 7], 1u);   // shared-mem atomic only
    }
    __syncthreads();
    for (int t = tid; t < NB; t += 256) C[(size_t)cb * NB + t] = hist[t];
}

// ---- k2: bf16 GEMM h = x @ W (blocks < GEMM_BLOCKS, unchanged code)
//      + prefix stage A (8 extra blocks): in-place column prefix of C over
//      64-row groups, per-group totals to S[p][bkt]. ----
__global__ __launch_bounds__(256) void gcn_gemm_prefA(const float* __restrict__ x,
                                                      const unsigned short* __restrict__ Wt,
                                                      unsigned short* __restrict__ h,
                                                      unsigned int* __restrict__ C,
                                                      unsigned int* __restrict__ S) {
    __shared__ unsigned short xs[BM][LDP];
    int tid = threadIdx.x;

    if (blockIdx.x >= GEMM_BLOCKS) {
        int p = blockIdx.x - GEMM_BLOCKS;
        #pragma unroll
        for (int c = 0; c < 4; ++c) {
            int t = tid + c * 256;      // bucket column owned by this thread
            unsigned int run = 0;
            for (int r = 0; r < RPB; r += 8) {
                unsigned int v[8];
                size_t base = ((size_t)(p * RPB + r)) * NB + t;
                #pragma unroll
                for (int j = 0; j < 8; ++j) v[j] = C[base + (size_t)j * NB];
                #pragma unroll
                for (int j = 0; j < 8; ++j) { C[base + (size_t)j * NB] = run; run += v[j]; }
            }
            S[p * NB + t] = run;
        }
        return;
    }

    // ---- gemm path: 4 waves, tile 128x64, K chunks of 64 ----
    int lane = tid & 63;
    int w = tid >> 6;
    int rowbase = blockIdx.x * BM;
    int r = tid >> 1, half = tid & 1;
    const float* xp = x + (size_t)(rowbase + r) * IN_DIM + half * 32;

    f32x4 acc[2][4] = {};

    for (int kb = 0; kb < IN_DIM; kb += KC) {
        __syncthreads();
        #pragma unroll
        for (int u = 0; u < 32; u += 8) {
            float4 v0 = *(const float4*)(xp + kb + u);
            float4 v1 = *(const float4*)(xp + kb + u + 4);
            bf16x8 pk;
            pk[0] = (short)f2bf(v0.x); pk[1] = (short)f2bf(v0.y);
            pk[2] = (short)f2bf(v0.z); pk[3] = (short)f2bf(v0.w);
            pk[4] = (short)f2bf(v1.x); pk[5] = (short)f2bf(v1.y);
            pk[6] = (short)f2bf(v1.z); pk[7] = (short)f2bf(v1.w);
            *(bf16x8*)&xs[r][half * 32 + u] = pk;
        }
        __syncthreads();
        #pragma unroll
        for (int ks = 0; ks < KC; ks += 32) {
            int klo = ks + (lane >> 4) * 8;
            int rl = (lane & 15);
            bf16x8 a0 = *(const bf16x8*)&xs[w * 32 + rl][klo];
            bf16x8 a1 = *(const bf16x8*)&xs[w * 32 + 16 + rl][klo];
            #pragma unroll
            for (int ct = 0; ct < 4; ++ct) {
                bf16x8 b = *(const bf16x8*)&Wt[(size_t)(ct * 16 + rl) * IN_DIM + kb + klo];
                acc[0][ct] = __builtin_amdgcn_mfma_f32_16x16x32_bf16(a0, b, acc[0][ct], 0, 0, 0);
                acc[1][ct] = __builtin_amdgcn_mfma_f32_16x16x32_bf16(a1, b, acc[1][ct], 0, 0, 0);
            }
        }
    }
    for (int rt = 0; rt < 2; ++rt) {
        int row0 = rowbase + w * 32 + rt * 16 + (lane >> 4) * 4;
        #pragma unroll
        for (int ct = 0; ct < 4; ++ct)
            #pragma unroll
            for (int rr = 0; rr < 4; ++rr) {
                int col = ct * 16 + (lane & 15);
                h[(size_t)(row0 + rr) * HID + col] = f2bf(acc[rt][ct][rr]);
            }
    }
}

// ---- k3: prefix stage B: scan S over p, then 1024-wide bucket scan ----
__global__ __launch_bounds__(1024) void gcn_prefB(unsigned int* __restrict__ S,
                                                  unsigned int* __restrict__ bstart) {
    __shared__ unsigned int sc[NB];
    int t = threadIdx.x;
    unsigned int run = 0;
    unsigned int v[PBLK];
    #pragma unroll
    for (int p = 0; p < PBLK; ++p) v[p] = S[p * NB + t];
    #pragma unroll
    for (int p = 0; p < PBLK; ++p) { S[p * NB + t] = run; run += v[p]; }
    sc[t] = run;
    __syncthreads();
    for (int off = 1; off < NB; off <<= 1) {
        unsigned int u = (t >= off) ? sc[t - off] : 0u;
        __syncthreads();
        sc[t] += u;
        __syncthreads();
    }
    bstart[t] = sc[t] - run;                 // exclusive
    if (t == NB - 1) bstart[NB] = sc[NB - 1]; // == N_EDGES
}

// ---- k4: scatter edges into bucket-contiguous order, LDS ticketing only ----
// part[pos] = src | (dst&127)<<17   (17+7 bits, fits u32)
__global__ __launch_bounds__(256) void gcn_scatter(const int* __restrict__ src,
                                                   const int* __restrict__ dst,
                                                   const unsigned int* __restrict__ C,
                                                   const unsigned int* __restrict__ S,
                                                   const unsigned int* __restrict__ bstart,
                                                   unsigned int* __restrict__ part) {
    __shared__ unsigned int off[NB];
    int tid = threadIdx.x, cb = blockIdx.x;
    int p = cb >> 6;  // cb / RPB
    for (int t = tid; t < NB; t += 256)
        off[t] = bstart[t] + S[p * NB + t] + C[(size_t)cb * NB + t];
    __syncthreads();
    int base = cb * EPB;
    #pragma unroll
    for (int u = 0; u < EPB / 256; ++u) {
        int i = base + u * 256 + tid;
        int d = dst[i];
        unsigned int pos = atomicAdd(&off[d >> 7], 1u);
        part[pos] = (unsigned int)src[i] | ((unsigned int)(d & (RNG - 1)) << 17);
    }
}

// ---- k5: per-node degree -> dinv (LDS bins, coalesced reads/writes) ----
__global__ __launch_bounds__(256) void gcn_deg(const unsigned int* __restrict__ part,
                                               const unsigned int* __restrict__ bstart,
                                               float* __restrict__ dinv) {
    __shared__ unsigned int bin[RNG];
    int tid = threadIdx.x, b = blockIdx.x;
    if (tid < RNG) bin[tid] = 0u;
    __syncthreads();
    unsigned int s0 = bstart[b], s1 = bstart[b + 1];
    for (unsigned int j = s0 + tid; j < s1; j += 256)
        atomicAdd(&bin[part[j] >> 17], 1u);
    __syncthreads();
    if (tid < RNG) dinv[b * RNG + tid] = rsqrtf((float)(bin[tid] + 1));
}

// ---- k6: range-local aggregation + relu + W_lin + per-graph logsoftmax ----
// Block b owns nodes [b*128, b*128+128) = graphs 4b..4b+3. LDS f32 acc tile.
// R1 post-mortem fix: 8 waves/block + 16-edge register batches so the
// part -> {dinv,h} chains overlap (MLP ~16) instead of serializing at VGPR=52.
#define LDA 65   // +1 pad keeps epilogue column reads conflict-free
#define AGG_THREADS 512
#define AGG_WAVES (AGG_THREADS / 64)
__global__ __launch_bounds__(AGG_THREADS) void gcn_agg(const unsigned short* __restrict__ h,
                                               const unsigned int* __restrict__ part,
                                               const unsigned int* __restrict__ bstart,
                                               const float* __restrict__ dinv,
                                               const float* __restrict__ b_conv,
                                               const float* __restrict__ W_lin,
                                               const float* __restrict__ b_lin,
                                               float* __restrict__ out) {
    __shared__ float acc[RNG][LDA];   // 33.3 KB
    int tid = threadIdx.x, lane = tid & 63, w = tid >> 6;
    int b = blockIdx.x;

    for (int t = tid; t < RNG * LDA; t += AGG_THREADS) ((float*)acc)[t] = 0.f;
    __syncthreads();

    unsigned int s0 = bstart[b], s1 = bstart[b + 1];
    unsigned int cntE = s1 - s0;
    unsigned int chunk = (cntE + AGG_WAVES - 1) / AGG_WAVES;
    unsigned int ws_ = s0 + (unsigned int)w * chunk;
    if (ws_ > s1) ws_ = s1;
    unsigned int we_ = ws_ + chunk;
    if (we_ > s1) we_ = s1;

    int q = lane >> 5, ln = lane & 31;   // half-wave per edge, 2 dims per lane
    unsigned int e = ws_;
    // main loop: 16 edges per wave-iteration (8 per half-wave), batched loads
    for (; e + 16 <= we_; e += 16) {
        unsigned int pr[8];
        #pragma unroll
        for (int j = 0; j < 8; ++j) pr[j] = part[e + 2 * j + q];
        int si[8], dl[8];
        #pragma unroll
        for (int j = 0; j < 8; ++j) { si[j] = pr[j] & 0x1FFFF; dl[j] = pr[j] >> 17; }
        float n[8];
        #pragma unroll
        for (int j = 0; j < 8; ++j) n[j] = dinv[si[j]];
        unsigned int hv[8];
        #pragma unroll
        for (int j = 0; j < 8; ++j)
            hv[j] = *(const unsigned int*)(h + (size_t)si[j] * HID + ln * 2);
        #pragma unroll
        for (int j = 0; j < 8; ++j) {
            atomicAdd(&acc[dl[j]][ln * 2 + 0], bf2f((unsigned short)(hv[j] & 0xffff)) * n[j]);
            atomicAdd(&acc[dl[j]][ln * 2 + 1], bf2f((unsigned short)(hv[j] >> 16)) * n[j]);
        }
    }
    for (; e < we_; e += 2) {
        unsigned int idx = e + q;
        if (idx < we_) {
            unsigned int pr = part[idx];
            int si = pr & 0x1FFFF, dl = pr >> 17;
            float n = dinv[si];
            unsigned int hv = *(const unsigned int*)(h + (size_t)si * HID + ln * 2);
            atomicAdd(&acc[dl][ln * 2 + 0], bf2f((unsigned short)(hv & 0xffff)) * n);
            atomicAdd(&acc[dl][ln * 2 + 1], bf2f((unsigned short)(hv >> 16)) * n);
        }
    }
    __syncthreads();

    // epilogue: waves 0..3 -> graph g = 4b+w (32 nodes), logits + logsoftmax
    if (w < 4) {
        int g = b * 4 + w;
        int nbase = b * RNG + w * 32;
        float bc = b_conv[lane];
        float l0 = 0.f, l1 = 0.f;
        for (int k = 0; k < 32; ++k) {
            int i = nbase + k;
            float di = dinv[i];
            float a = acc[w * 32 + k][lane];
            float hs = bf2f(h[(size_t)i * HID + lane]);
            float ttl = fmaf(di, hs, a);                  // sum_s ds*h_s + di*h_i
            float v = fmaxf(fmaf(ttl, di, bc), 0.f);
            l0 = fmaf(v, W_lin[k * HID + lane], l0);
            l1 = fmaf(v, W_lin[HID * NPG + k * HID + lane], l1);
        }
        #pragma unroll
        for (int d2 = 32; d2 > 0; d2 >>= 1) {
            l0 += __shfl_down(l0, d2);
            l1 += __shfl_down(l1, d2);
        }
        if (lane == 0) {
            float A = l0 + b_lin[0];
            float B = l1 + b_lin[1];
            float m = fmaxf(A, B);
            float lse = m + logf(expf(A - m) + expf(B - m));
            out[g * 2 + 0] = A - lse;
            out[g * 2 + 1] = B - lse;
        }
    }
}

extern "C" void kernel_launch(void* const* d_in, const int* in_sizes, int n_in,
                              void* d_out, int out_size, void* d_ws, size_t ws_size,
                              hipStream_t stream) {
    const float* x  = (const float*)d_in[0];
    const int* ei   = (const int*)d_in[1];
    const float* Wc = (const float*)d_in[2];
    const float* bc = (const float*)d_in[3];
    const float* Wl = (const float*)d_in[4];
    const float* bl = (const float*)d_in[5];
    float* out = (float*)d_out;

    char* ws = (char*)d_ws;
    unsigned short* Wt   = (unsigned short*)(ws);                 // 96 KB
    float*          dinv = (float*)(ws + (128 << 10));            // 512 KB
    unsigned int*  bstart= (unsigned int*)(ws + (640 << 10));     // 4.1 KB
    unsigned int*  S     = (unsigned int*)(ws + (656 << 10));     // 32 KB
    unsigned int*  C     = (unsigned int*)(ws + (1024 << 10));    // 2 MB
    unsigned int*  part  = (unsigned int*)(ws + (3u << 20));      // 8 MB
    unsigned short* h    = (unsigned short*)(ws + (11u << 20));   // 16 MB

    const int* srcIdx = ei;
    const int* dstIdx = ei + N_EDGES;

    gcn_prep_count<<<PREP_BLK + NCB, 256, 0, stream>>>(Wc, Wt, dstIdx, C);
    gcn_gemm_prefA<<<GEMM_BLOCKS + PBLK, 256, 0, stream>>>(x, Wt, h, C, S);
    gcn_prefB<<<1, 1024, 0, stream>>>(S, bstart);
    gcn_scatter<<<NCB, 256, 0, stream>>>(srcIdx, dstIdx, C, S, bstart, part);
    gcn_deg<<<NB, 256, 0, stream>>>(part, bstart, dinv);
    gcn_agg<<<NB, AGG_THREADS, 0, stream>>>(h, part, bstart, dinv, bc, Wl, bl, out);
}

// Round 3
// 259.117 us; speedup vs baseline: 3.3487x; 3.3487x over previous
//
#include <hip/hip_runtime.h>
#include <hip/hip_bf16.h>

#define N_NODES 131072
#define N_EDGES 2097152
#define IN_DIM 768
#define HID 64
#define NPG 32
#define NGRAPH (N_NODES / NPG)   // 4096

#define BM 128
#define KC 64
#define LDP (KC + 8)
#define GEMM_BLOCKS (N_NODES / BM)    // 1024

// ---- radix partition geometry: ranges of 128 nodes = 4 whole graphs ----
#define RNG 128
#define NB (N_NODES / RNG)            // 1024 buckets
#define EPB 4096                      // edges per count/scatter block
#define NCB (N_EDGES / EPB)           // 512 blocks
#define PBLK 8                        // prefix stage-A blocks
#define RPB (NCB / PBLK)              // 64 rows per stage-A block
#define PREP_BLK 192                  // blocks for W transpose

typedef __attribute__((ext_vector_type(8))) short bf16x8;
typedef __attribute__((ext_vector_type(4))) float f32x4;

static __device__ __forceinline__ unsigned short f2bf(float f) {
    __hip_bfloat16 h = __float2bfloat16(f);  // hardware RNE cvt
    return *reinterpret_cast<unsigned short*>(&h);
}
static __device__ __forceinline__ float bf2f(unsigned short s) {
    return __uint_as_float(((unsigned int)s) << 16);
}

// ---- k1: W transpose (blocks < PREP_BLK) + per-block bucket histogram ----
__global__ __launch_bounds__(256) void gcn_prep_count(const float* __restrict__ W,
                                                      unsigned short* __restrict__ Wt,
                                                      const int* __restrict__ dst,
                                                      unsigned int* __restrict__ C) {
    __shared__ unsigned int hist[NB];
    int tid = threadIdx.x;
    if (blockIdx.x < PREP_BLK) {
        int i = blockIdx.x * 256 + tid;
        if (i < IN_DIM * HID) {
            int k = i >> 6, n = i & 63;
            Wt[n * IN_DIM + k] = f2bf(W[i]);
        }
        return;
    }
    int cb = blockIdx.x - PREP_BLK;
    for (int t = tid; t < NB; t += 256) hist[t] = 0u;
    __syncthreads();
    int base = cb * EPB;
    #pragma unroll
    for (int u = 0; u < EPB / 256; ++u) {
        int d = dst[base + u * 256 + tid];
        atomicAdd(&hist[d >> 7], 1u);   // shared-mem u32 atomic only
    }
    __syncthreads();
    for (int t = tid; t < NB; t += 256) C[(size_t)cb * NB + t] = hist[t];
}

// ---- k2: bf16 GEMM h = x @ W + prefix stage A (8 extra blocks) ----
__global__ __launch_bounds__(256) void gcn_gemm_prefA(const float* __restrict__ x,
                                                      const unsigned short* __restrict__ Wt,
                                                      unsigned short* __restrict__ h,
                                                      unsigned int* __restrict__ C,
                                                      unsigned int* __restrict__ S) {
    __shared__ unsigned short xs[BM][LDP];
    int tid = threadIdx.x;

    if (blockIdx.x >= GEMM_BLOCKS) {
        int p = blockIdx.x - GEMM_BLOCKS;
        #pragma unroll
        for (int c = 0; c < 4; ++c) {
            int t = tid + c * 256;
            unsigned int run = 0;
            for (int r = 0; r < RPB; r += 8) {
                unsigned int v[8];
                size_t base = ((size_t)(p * RPB + r)) * NB + t;
                #pragma unroll
                for (int j = 0; j < 8; ++j) v[j] = C[base + (size_t)j * NB];
                #pragma unroll
                for (int j = 0; j < 8; ++j) { C[base + (size_t)j * NB] = run; run += v[j]; }
            }
            S[p * NB + t] = run;
        }
        return;
    }

    int lane = tid & 63;
    int w = tid >> 6;
    int rowbase = blockIdx.x * BM;
    int r = tid >> 1, half = tid & 1;
    const float* xp = x + (size_t)(rowbase + r) * IN_DIM + half * 32;

    f32x4 acc[2][4] = {};

    for (int kb = 0; kb < IN_DIM; kb += KC) {
        __syncthreads();
        #pragma unroll
        for (int u = 0; u < 32; u += 8) {
            float4 v0 = *(const float4*)(xp + kb + u);
            float4 v1 = *(const float4*)(xp + kb + u + 4);
            bf16x8 pk;
            pk[0] = (short)f2bf(v0.x); pk[1] = (short)f2bf(v0.y);
            pk[2] = (short)f2bf(v0.z); pk[3] = (short)f2bf(v0.w);
            pk[4] = (short)f2bf(v1.x); pk[5] = (short)f2bf(v1.y);
            pk[6] = (short)f2bf(v1.z); pk[7] = (short)f2bf(v1.w);
            *(bf16x8*)&xs[r][half * 32 + u] = pk;
        }
        __syncthreads();
        #pragma unroll
        for (int ks = 0; ks < KC; ks += 32) {
            int klo = ks + (lane >> 4) * 8;
            int rl = (lane & 15);
            bf16x8 a0 = *(const bf16x8*)&xs[w * 32 + rl][klo];
            bf16x8 a1 = *(const bf16x8*)&xs[w * 32 + 16 + rl][klo];
            #pragma unroll
            for (int ct = 0; ct < 4; ++ct) {
                bf16x8 b = *(const bf16x8*)&Wt[(size_t)(ct * 16 + rl) * IN_DIM + kb + klo];
                acc[0][ct] = __builtin_amdgcn_mfma_f32_16x16x32_bf16(a0, b, acc[0][ct], 0, 0, 0);
                acc[1][ct] = __builtin_amdgcn_mfma_f32_16x16x32_bf16(a1, b, acc[1][ct], 0, 0, 0);
            }
        }
    }
    for (int rt = 0; rt < 2; ++rt) {
        int row0 = rowbase + w * 32 + rt * 16 + (lane >> 4) * 4;
        #pragma unroll
        for (int ct = 0; ct < 4; ++ct)
            #pragma unroll
            for (int rr = 0; rr < 4; ++rr) {
                int col = ct * 16 + (lane & 15);
                h[(size_t)(row0 + rr) * HID + col] = f2bf(acc[rt][ct][rr]);
            }
    }
}

// ---- k3: prefix stage B ----
__global__ __launch_bounds__(1024) void gcn_prefB(unsigned int* __restrict__ S,
                                                  unsigned int* __restrict__ bstart) {
    __shared__ unsigned int sc[NB];
    int t = threadIdx.x;
    unsigned int run = 0;
    unsigned int v[PBLK];
    #pragma unroll
    for (int p = 0; p < PBLK; ++p) v[p] = S[p * NB + t];
    #pragma unroll
    for (int p = 0; p < PBLK; ++p) { S[p * NB + t] = run; run += v[p]; }
    sc[t] = run;
    __syncthreads();
    for (int off = 1; off < NB; off <<= 1) {
        unsigned int u = (t >= off) ? sc[t - off] : 0u;
        __syncthreads();
        sc[t] += u;
        __syncthreads();
    }
    bstart[t] = sc[t] - run;                 // exclusive
    if (t == NB - 1) bstart[NB] = sc[NB - 1]; // == N_EDGES
}

// ---- k4: scatter edges into bucket-contiguous order (LDS ticketing) ----
// part[pos] = src | (dst&127)<<17
__global__ __launch_bounds__(256) void gcn_scatter(const int* __restrict__ src,
                                                   const int* __restrict__ dst,
                                                   const unsigned int* __restrict__ C,
                                                   const unsigned int* __restrict__ S,
                                                   const unsigned int* __restrict__ bstart,
                                                   unsigned int* __restrict__ part) {
    __shared__ unsigned int off[NB];
    int tid = threadIdx.x, cb = blockIdx.x;
    int p = cb >> 6;
    for (int t = tid; t < NB; t += 256)
        off[t] = bstart[t] + S[p * NB + t] + C[(size_t)cb * NB + t];
    __syncthreads();
    int base = cb * EPB;
    #pragma unroll
    for (int u = 0; u < EPB / 256; ++u) {
        int i = base + u * 256 + tid;
        int d = dst[i];
        unsigned int pos = atomicAdd(&off[d >> 7], 1u);
        part[pos] = (unsigned int)src[i] | ((unsigned int)(d & (RNG - 1)) << 17);
    }
}

// ---- k5: second-level sort -> per-node CSR (part2, nstart) + dinv ----
// One block per bucket: 128-bin histogram (degree), scan, ticket-scatter.
__global__ __launch_bounds__(256) void gcn_sort2(const unsigned int* __restrict__ part,
                                                 const unsigned int* __restrict__ bstart,
                                                 unsigned int* __restrict__ part2,
                                                 unsigned int* __restrict__ nstart,
                                                 float* __restrict__ dinv) {
    __shared__ unsigned int hist[RNG];
    __shared__ unsigned int sc[RNG];
    __shared__ unsigned int off[RNG];
    int tid = threadIdx.x, b = blockIdx.x;
    if (tid < RNG) hist[tid] = 0u;
    __syncthreads();
    unsigned int s0 = bstart[b], s1 = bstart[b + 1];
    for (unsigned int j = s0 + tid; j < s1; j += 256)
        atomicAdd(&hist[part[j] >> 17], 1u);
    __syncthreads();
    if (tid < RNG) sc[tid] = hist[tid];
    __syncthreads();
    #pragma unroll
    for (int o = 1; o < RNG; o <<= 1) {
        unsigned int u = (tid < RNG && tid >= o) ? sc[tid - o] : 0u;
        __syncthreads();
        if (tid < RNG) sc[tid] += u;
        __syncthreads();
    }
    if (tid < RNG) {
        unsigned int excl = sc[tid] - hist[tid];
        nstart[b * RNG + tid] = s0 + excl;
        off[tid] = s0 + excl;
        dinv[b * RNG + tid] = rsqrtf((float)(hist[tid] + 1));
    }
    if (b == NB - 1 && tid == 0) nstart[N_NODES] = N_EDGES;
    __syncthreads();
    for (unsigned int j = s0 + tid; j < s1; j += 256) {
        unsigned int pr = part[j];
        unsigned int pos = atomicAdd(&off[pr >> 17], 1u);
        part2[pos] = pr & 0x1FFFF;
    }
}

// ---- k6: CSR aggregation + relu + W_lin + per-graph logsoftmax ----
// Block = 1 graph (512 thr, 8 waves); wave = 4 nodes; register accumulation,
// shfl-broadcast neighbor lists. ZERO atomics (R2 post-mortem: LDS f32
// atomics serialized at ~200 cy/instr and were the entire 692 us).
__global__ __launch_bounds__(512) void gcn_agg(const unsigned short* __restrict__ h,
                                               const unsigned int* __restrict__ part2,
                                               const unsigned int* __restrict__ nstart,
                                               const float* __restrict__ dinv,
                                               const float* __restrict__ b_conv,
                                               const float* __restrict__ W_lin,
                                               const float* __restrict__ b_lin,
                                               float* __restrict__ out) {
    __shared__ float p0s[8], p1s[8];
    int tid = threadIdx.x, lane = tid & 63, w = tid >> 6;
    int g = blockIdx.x;
    float bc = b_conv[lane];
    float l0 = 0.f, l1 = 0.f;

    #pragma unroll
    for (int k = 0; k < 4; ++k) {
        int node = w * 4 + k;                 // 0..31 within graph
        int i = g * NPG + node;
        unsigned int st = nstart[i];
        unsigned int en = nstart[i + 1];
        int c = (int)(en - st);
        float di = dinv[i];
        float acc = di * bf2f(h[(size_t)i * HID + lane]);  // self-loop term
        for (int base = 0; base < c; base += 64) {
            int m = min(64, c - base);
            int sidx = 0;
            float dsv = 0.f;
            if (lane < m) {
                sidx = (int)part2[st + base + lane];
                dsv = dinv[sidx];
            }
            int e = 0;
            for (; e + 4 <= m; e += 4) {
                int s0 = __shfl(sidx, e + 0);
                int s1 = __shfl(sidx, e + 1);
                int s2 = __shfl(sidx, e + 2);
                int s3 = __shfl(sidx, e + 3);
                float d0 = __shfl(dsv, e + 0);
                float d1 = __shfl(dsv, e + 1);
                float d2 = __shfl(dsv, e + 2);
                float d3 = __shfl(dsv, e + 3);
                float v0 = bf2f(h[(size_t)s0 * HID + lane]);
                float v1 = bf2f(h[(size_t)s1 * HID + lane]);
                float v2 = bf2f(h[(size_t)s2 * HID + lane]);
                float v3 = bf2f(h[(size_t)s3 * HID + lane]);
                acc = fmaf(d0, v0, acc);
                acc = fmaf(d1, v1, acc);
                acc = fmaf(d2, v2, acc);
                acc = fmaf(d3, v3, acc);
            }
            for (; e < m; ++e) {
                int s = __shfl(sidx, e);
                float ds = __shfl(dsv, e);
                acc = fmaf(ds, bf2f(h[(size_t)s * HID + lane]), acc);
            }
        }
        float v = fmaxf(fmaf(acc, di, bc), 0.f);
        l0 = fmaf(v, W_lin[node * HID + lane], l0);
        l1 = fmaf(v, W_lin[HID * NPG + node * HID + lane], l1);
    }
    #pragma unroll
    for (int d = 32; d > 0; d >>= 1) {
        l0 += __shfl_down(l0, d);
        l1 += __shfl_down(l1, d);
    }
    if (lane == 0) { p0s[w] = l0; p1s[w] = l1; }
    __syncthreads();
    if (tid == 0) {
        float A = b_lin[0], B = b_lin[1];
        #pragma unroll
        for (int j = 0; j < 8; ++j) { A += p0s[j]; B += p1s[j]; }
        float m = fmaxf(A, B);
        float lse = m + logf(expf(A - m) + expf(B - m));
        out[g * 2 + 0] = A - lse;
        out[g * 2 + 1] = B - lse;
    }
}

extern "C" void kernel_launch(void* const* d_in, const int* in_sizes, int n_in,
                              void* d_out, int out_size, void* d_ws, size_t ws_size,
                              hipStream_t stream) {
    const float* x  = (const float*)d_in[0];
    const int* ei   = (const int*)d_in[1];
    const float* Wc = (const float*)d_in[2];
    const float* bc = (const float*)d_in[3];
    const float* Wl = (const float*)d_in[4];
    const float* bl = (const float*)d_in[5];
    float* out = (float*)d_out;

    char* ws = (char*)d_ws;
    unsigned short* Wt   = (unsigned short*)(ws);                 // 96 KB
    float*          dinv = (float*)(ws + (128 << 10));            // 512 KB
    unsigned int*  bstart= (unsigned int*)(ws + (640 << 10));     // 4.1 KB
    unsigned int*  S     = (unsigned int*)(ws + (656 << 10));     // 32 KB
    unsigned int*  C     = (unsigned int*)(ws + (1024 << 10));    // 2 MB
    unsigned int*  part  = (unsigned int*)(ws + (3u << 20));      // 8 MB
    unsigned short* h    = (unsigned short*)(ws + (11u << 20));   // 16 MB
    unsigned int*  part2 = (unsigned int*)(ws + (27u << 20));     // 8 MB
    unsigned int*  nstart= (unsigned int*)(ws + (35u << 20));     // 512 KB + 4
    // total ~35.6 MB < previous proven 44.5 MB footprint

    const int* srcIdx = ei;
    const int* dstIdx = ei + N_EDGES;

    gcn_prep_count<<<PREP_BLK + NCB, 256, 0, stream>>>(Wc, Wt, dstIdx, C);
    gcn_gemm_prefA<<<GEMM_BLOCKS + PBLK, 256, 0, stream>>>(x, Wt, h, C, S);
    gcn_prefB<<<1, 1024, 0, stream>>>(S, bstart);
    gcn_scatter<<<NCB, 256, 0, stream>>>(srcIdx, dstIdx, C, S, bstart, part);
    gcn_sort2<<<NB, 256, 0, stream>>>(part, bstart, part2, nstart, dinv);
    gcn_agg<<<NGRAPH, 512, 0, stream>>>(h, part2, nstart, dinv, bc, Wl, bl, out);
}